// Round 13
// baseline (1904.330 us; speedup 1.0000x reference)
//
#include <hip/hip_runtime.h>
#include <stdint.h>

#define E_ 8
#define H_ 2048
#define I_ 4096
#define T_ 1024
#define N1_ (2 * I_) /* 8192 */

typedef unsigned short ushort_t;
typedef _Float16 half_t;
typedef __attribute__((ext_vector_type(2))) _Float16 h2;
typedef __attribute__((ext_vector_type(8))) _Float16 f16x8;
typedef __attribute__((ext_vector_type(4))) float f32x4;

// pack two fp32 -> two f16 (RTZ) in one dword: 1 VALU op
__device__ __forceinline__ uint32_t pk2h(float a, float b) {
    auto r = __builtin_amdgcn_cvt_pkrtz(a, b);
    uint32_t u;
    __builtin_memcpy(&u, &r, 4);
    return u;
}

// per-K-step scale: fold gscale*blockscale/64 into a packed f16 pair
__device__ __forceinline__ h2 mk_ss(float sv) {
    half_t h = (half_t)(sv * 0.015625f); // /64: LUT stores value*64
    h2 r; r.x = h; r.y = h;
    return r;
}

// ---- dequant 4 packed words (1 byte each = 2 fp4 codes) -> 4 dwords of 2 scaled f16 ----
__device__ __forceinline__ uint4 dq_quad(const int wt[4], h2 ss) {
    uint32_t t0 = __builtin_amdgcn_perm((uint32_t)wt[1], (uint32_t)wt[0], 0x0C0C0400u);
    uint32_t t1 = __builtin_amdgcn_perm((uint32_t)wt[3], (uint32_t)wt[2], 0x04000C0Cu);
    uint32_t w4 = t0 | t1;
    const uint32_t T_LO = 0x56545000u; // codes 0..3 f16-hi of val*64
    const uint32_t T_HI = 0x5E5C5A58u; // codes 4..7
    uint32_t selL = w4 & 0x07070707u;
    uint32_t selH = (w4 >> 4) & 0x07070707u;
    uint32_t hiL = __builtin_amdgcn_perm(T_HI, T_LO, selL) | ((w4 & 0x08080808u) << 4);
    uint32_t hiH = __builtin_amdgcn_perm(T_HI, T_LO, selH) | (w4 & 0x80808080u);
    uint32_t p0 = __builtin_amdgcn_perm(hiH, hiL, 0x040C000Cu);
    uint32_t p1 = __builtin_amdgcn_perm(hiH, hiL, 0x050C010Cu);
    uint32_t p2 = __builtin_amdgcn_perm(hiH, hiL, 0x060C020Cu);
    uint32_t p3 = __builtin_amdgcn_perm(hiH, hiL, 0x070C030Cu);
    uint4 q;
    h2 r0 = *(h2*)&p0 * ss; __builtin_memcpy(&q.x, &r0, 4);
    h2 r1 = *(h2*)&p1 * ss; __builtin_memcpy(&q.y, &r1, 4);
    h2 r2 = *(h2*)&p2 * ss; __builtin_memcpy(&q.z, &r2, 4);
    h2 r3 = *(h2*)&p3 * ss; __builtin_memcpy(&q.w, &r3, 4);
    return q;
}

// ==================== GEMM1: x(fp32) @ dequant(Wgu) + silu ====================
// Round-5 verified structure + 2-deep global prefetch: loads for tile t+2
// issue at phase t -> ~2.5 consume-phases of latency cover (was ~1). Two
// statically-named register sets (rule #20: no runtime-indexed pipeline
// arrays -> no scratch). One barrier per phase; LDS[i] written only
// post-barrier after its last pre-barrier read.
__global__ __launch_bounds__(512, 4) void gemm1_kernel(
    const float* __restrict__ x,
    const int* __restrict__ gup,
    const float* __restrict__ gus,
    const float* __restrict__ gscale_p,
    ushort_t* __restrict__ inter,
    int e0) {
    __shared__ __align__(16) ushort_t As[2][256 * 40];
    __shared__ __align__(16) ushort_t Bs[2][128 * 40];

    const int tid = threadIdx.x;
    const int lane = tid & 63, wv = tid >> 6;
    const int quad = lane >> 4, c16 = lane & 15;
    const int mw = wv >> 1, nw = wv & 1;
    const int zloc = blockIdx.z, e = e0 + zloc;
    const int mBase = blockIdx.y * 256, nTile = blockIdx.x;
    const float gsc = gscale_p[0];

    const int kq = (tid >> 4) & 3;
    const int bn = (tid & 15) | ((tid >> 6) << 4);
    const int colg = nTile * 64 + (bn & 63) + ((bn >> 6) << 12);
    const int* bptr = gup + (size_t)e * (H_ / 2) * N1_ + (size_t)(kq * 4) * N1_ + colg;
    const float* sptr = gus + (size_t)e * (H_ / 16) * N1_ + (size_t)(kq >> 1) * N1_ + colg;

    const int arow = tid >> 2, seg = tid & 3;
    const float* ap = x + (size_t)(e * T_ + mBase + arow) * H_ + seg * 8;

    f32x4 accg[4][2], accu[4][2];
    const f32x4 z4 = {0.f, 0.f, 0.f, 0.f};
#pragma unroll
    for (int f = 0; f < 4; ++f)
#pragma unroll
        for (int b = 0; b < 2; ++b) { accg[f][b] = z4; accu[f][b] = z4; }

    float4 faA[4], faB[4]; int wtA[4], wtB[4]; float svA, svB;

#define G1_LOAD(FA, WT, SV, t) do { \
    FA[0] = *(const float4*)(ap + (size_t)(t) * 32); \
    FA[1] = *(const float4*)(ap + (size_t)(t) * 32 + 4); \
    FA[2] = *(const float4*)(ap + (size_t)128 * H_ + (size_t)(t) * 32); \
    FA[3] = *(const float4*)(ap + (size_t)128 * H_ + (size_t)(t) * 32 + 4); \
    const int* bp_ = bptr + (size_t)(t) * 16 * N1_; \
    WT[0] = bp_[0]; WT[1] = bp_[(size_t)N1_]; \
    WT[2] = bp_[2 * (size_t)N1_]; WT[3] = bp_[3 * (size_t)N1_]; \
    SV = sptr[(size_t)(t) * 2 * N1_] * gsc; \
} while (0)

#define G1_STAGE(FA, WT, SV, L) do { \
    uint4 d0_, d1_; \
    d0_.x = pk2h(FA[0].x, FA[0].y); d0_.y = pk2h(FA[0].z, FA[0].w); \
    d0_.z = pk2h(FA[1].x, FA[1].y); d0_.w = pk2h(FA[1].z, FA[1].w); \
    d1_.x = pk2h(FA[2].x, FA[2].y); d1_.y = pk2h(FA[2].z, FA[2].w); \
    d1_.z = pk2h(FA[3].x, FA[3].y); d1_.w = pk2h(FA[3].z, FA[3].w); \
    *(uint4*)(&As[L][arow * 40 + seg * 8]) = d0_; \
    *(uint4*)(&As[L][(arow + 128) * 40 + seg * 8]) = d1_; \
    uint4 q_ = dq_quad(WT, mk_ss(SV)); \
    *(uint4*)(&Bs[L][bn * 40 + kq * 8]) = q_; \
} while (0)

#define G1_CONSUME(L) do { \
    f16x8 bg0 = *(const f16x8*)(&Bs[L][(nw * 32 + c16) * 40 + quad * 8]); \
    f16x8 bg1 = *(const f16x8*)(&Bs[L][(nw * 32 + 16 + c16) * 40 + quad * 8]); \
    f16x8 bu0 = *(const f16x8*)(&Bs[L][(64 + nw * 32 + c16) * 40 + quad * 8]); \
    f16x8 bu1 = *(const f16x8*)(&Bs[L][(64 + nw * 32 + 16 + c16) * 40 + quad * 8]); \
    _Pragma("unroll") \
    for (int f = 0; f < 4; ++f) { \
        f16x8 af = *(const f16x8*)(&As[L][(mw * 64 + f * 16 + c16) * 40 + quad * 8]); \
        accg[f][0] = __builtin_amdgcn_mfma_f32_16x16x32_f16(af, bg0, accg[f][0], 0, 0, 0); \
        accg[f][1] = __builtin_amdgcn_mfma_f32_16x16x32_f16(af, bg1, accg[f][1], 0, 0, 0); \
        accu[f][0] = __builtin_amdgcn_mfma_f32_16x16x32_f16(af, bu0, accu[f][0], 0, 0, 0); \
        accu[f][1] = __builtin_amdgcn_mfma_f32_16x16x32_f16(af, bu1, accu[f][1], 0, 0, 0); \
    } \
} while (0)

    const int NT = H_ / 32; // 64, even
    G1_LOAD(faA, wtA, svA, 0);
    G1_LOAD(faB, wtB, svB, 1);
    G1_STAGE(faA, wtA, svA, 0);
    __syncthreads();
    for (int kt = 0; kt < NT; kt += 2) {
        // even phase: consume LDS0 (t=kt); B-set holds t=kt+1; A-set free -> load t=kt+2
        if (kt + 2 < NT) G1_LOAD(faA, wtA, svA, kt + 2);
        G1_CONSUME(0);
        G1_STAGE(faB, wtB, svB, 1);
        __syncthreads();
        // odd phase: consume LDS1 (t=kt+1); A-set holds t=kt+2; B-set free -> load t=kt+3
        if (kt + 3 < NT) G1_LOAD(faB, wtB, svB, kt + 3);
        G1_CONSUME(1);
        if (kt + 2 < NT) { G1_STAGE(faA, wtA, svA, 0); __syncthreads(); }
    }
#undef G1_LOAD
#undef G1_STAGE
#undef G1_CONSUME

    // epilogue: inter = up * silu(gate), stored as f16
    ushort_t* ip = inter + (size_t)zloc * T_ * I_;
#pragma unroll
    for (int f = 0; f < 4; ++f)
#pragma unroll
        for (int b = 0; b < 2; ++b)
#pragma unroll
            for (int r = 0; r < 4; ++r) {
                int row = mBase + mw * 64 + f * 16 + quad * 4 + r;
                int col = nTile * 64 + nw * 32 + b * 16 + c16;
                float g = accg[f][b][r];
                float u = accu[f][b][r];
                float v = u * g / (1.f + __expf(-g));
                half_t hv = (half_t)v;
                ushort_t hu;
                __builtin_memcpy(&hu, &hv, 2);
                ip[(size_t)row * I_ + col] = hu;
            }
}

// ==================== GEMM2: inter(f16) @ dequant(Wd) -> fp32 ====================
// Round-5 verified form (padded 80B-row As, reg-staged A) + 2-deep prefetch.
__global__ __launch_bounds__(512, 4) void gemm2_kernel(
    const ushort_t* __restrict__ inter,
    const int* __restrict__ dp,
    const float* __restrict__ dsc,
    const float* __restrict__ gscale_p,
    float* __restrict__ out,
    int e0) {
    __shared__ __align__(16) ushort_t As[2][256 * 40];
    __shared__ __align__(16) ushort_t Bs[2][128 * 40];

    const int tid = threadIdx.x;
    const int lane = tid & 63, wv = tid >> 6;
    const int quad = lane >> 4, c16 = lane & 15;
    const int mw = wv >> 1, nw = wv & 1;
    const int zloc = blockIdx.z, e = e0 + zloc;
    const int mBase = blockIdx.y * 256, nBase = blockIdx.x * 128;
    const float gsc = gscale_p[0];

    const int kq = (tid >> 4) & 3;
    const int bn = (tid & 15) | ((tid >> 6) << 4);
    const int col = nBase + bn;
    const int* bptr = dp + (size_t)e * (I_ / 2) * H_ + (size_t)(kq * 4) * H_ + col;
    const float* sptr = dsc + (size_t)e * (I_ / 16) * H_ + (size_t)(kq >> 1) * H_ + col;

    const int arow = tid >> 2, seg = tid & 3;
    const ushort_t* ap = inter + (size_t)(zloc * T_ + mBase + arow) * I_ + seg * 8;

    f32x4 acc[4][4];
    const f32x4 z4 = {0.f, 0.f, 0.f, 0.f};
#pragma unroll
    for (int f = 0; f < 4; ++f)
#pragma unroll
        for (int b = 0; b < 4; ++b) acc[f][b] = z4;

    uint4 vaA[2], vaB[2]; int wtA[4], wtB[4]; float svA, svB;

#define G2_LOAD(VA, WT, SV, t) do { \
    VA[0] = *(const uint4*)(ap + (size_t)(t) * 32); \
    VA[1] = *(const uint4*)(ap + (size_t)128 * I_ + (size_t)(t) * 32); \
    const int* bp_ = bptr + (size_t)(t) * 16 * H_; \
    WT[0] = bp_[0]; WT[1] = bp_[(size_t)H_]; \
    WT[2] = bp_[2 * (size_t)H_]; WT[3] = bp_[3 * (size_t)H_]; \
    SV = sptr[(size_t)(t) * 2 * H_] * gsc; \
} while (0)

#define G2_STAGE(VA, WT, SV, L) do { \
    *(uint4*)(&As[L][arow * 40 + seg * 8]) = VA[0]; \
    *(uint4*)(&As[L][(arow + 128) * 40 + seg * 8]) = VA[1]; \
    uint4 q_ = dq_quad(WT, mk_ss(SV)); \
    *(uint4*)(&Bs[L][bn * 40 + kq * 8]) = q_; \
} while (0)

#define G2_CONSUME(L) do { \
    f16x8 bfr[4]; \
    _Pragma("unroll") \
    for (int b = 0; b < 4; ++b) \
        bfr[b] = *(const f16x8*)(&Bs[L][(nw * 64 + b * 16 + c16) * 40 + quad * 8]); \
    _Pragma("unroll") \
    for (int f = 0; f < 4; ++f) { \
        f16x8 af = *(const f16x8*)(&As[L][(mw * 64 + f * 16 + c16) * 40 + quad * 8]); \
        _Pragma("unroll") \
        for (int b = 0; b < 4; ++b) \
            acc[f][b] = __builtin_amdgcn_mfma_f32_16x16x32_f16(af, bfr[b], acc[f][b], 0, 0, 0); \
    } \
} while (0)

    const int NT = I_ / 32; // 128, even
    G2_LOAD(vaA, wtA, svA, 0);
    G2_LOAD(vaB, wtB, svB, 1);
    G2_STAGE(vaA, wtA, svA, 0);
    __syncthreads();
    for (int kt = 0; kt < NT; kt += 2) {
        if (kt + 2 < NT) G2_LOAD(vaA, wtA, svA, kt + 2);
        G2_CONSUME(0);
        G2_STAGE(vaB, wtB, svB, 1);
        __syncthreads();
        if (kt + 3 < NT) G2_LOAD(vaB, wtB, svB, kt + 3);
        G2_CONSUME(1);
        if (kt + 2 < NT) { G2_STAGE(vaA, wtA, svA, 0); __syncthreads(); }
    }
#undef G2_LOAD
#undef G2_STAGE
#undef G2_CONSUME

#pragma unroll
    for (int f = 0; f < 4; ++f)
#pragma unroll
        for (int b = 0; b < 4; ++b)
#pragma unroll
            for (int r = 0; r < 4; ++r) {
                int row = mBase + mw * 64 + f * 16 + quad * 4 + r;
                int c = nBase + nw * 64 + b * 16 + c16;
                out[(size_t)(e * T_ + row) * H_ + c] = acc[f][b][r];
            }
}

extern "C" void kernel_launch(void* const* d_in, const int* in_sizes, int n_in,
                              void* d_out, int out_size, void* d_ws, size_t ws_size,
                              hipStream_t stream) {
    const float* x = (const float*)d_in[0];
    const int* gup = (const int*)d_in[1];
    const float* gus = (const float*)d_in[2];
    const float* gug = (const float*)d_in[3];
    const int* dp = (const int*)d_in[4];
    const float* dsc = (const float*)d_in[5];
    const float* dg = (const float*)d_in[6];
    float* out = (float*)d_out;
    ushort_t* inter = (ushort_t*)d_ws;

    const size_t per_e = (size_t)T_ * I_ * 2;
    int C = 8;
    if (ws_size < 8 * per_e) C = (ws_size >= 4 * per_e) ? 4 : (ws_size >= 2 * per_e) ? 2 : 1;

    for (int e0 = 0; e0 < E_; e0 += C) {
        gemm1_kernel<<<dim3(I_ / 64, T_ / 256, C), 512, 0, stream>>>(x, gup, gus, gug, inter, e0);
        gemm2_kernel<<<dim3(H_ / 128, T_ / 256, C), 512, 0, stream>>>(inter, dp, dsc, dg, out, e0);
    }
}

// Round 15
// 964.402 us; speedup vs baseline: 1.9746x; 1.9746x over previous
//
#include <hip/hip_runtime.h>
#include <stdint.h>

#define E_ 8
#define H_ 2048
#define I_ 4096
#define T_ 1024
#define N1_ (2 * I_) /* 8192 */

typedef unsigned short ushort_t;
typedef _Float16 half_t;
typedef __attribute__((ext_vector_type(2))) _Float16 h2;
typedef __attribute__((ext_vector_type(8))) _Float16 f16x8;
typedef __attribute__((ext_vector_type(4))) float f32x4;

// pack two fp32 -> two f16 (RTZ) in one dword: 1 VALU op
__device__ __forceinline__ uint32_t pk2h(float a, float b) {
    auto r = __builtin_amdgcn_cvt_pkrtz(a, b);
    uint32_t u;
    __builtin_memcpy(&u, &r, 4);
    return u;
}

// per-K-step scale: fold gscale*blockscale/64 into a packed f16 pair
__device__ __forceinline__ h2 mk_ss(float sv) {
    half_t h = (half_t)(sv * 0.015625f); // /64: LUT stores value*64
    h2 r; r.x = h; r.y = h;
    return r;
}

// ---- dequant 4 packed words (1 byte each = 2 fp4 codes) -> 4 dwords of 2 scaled f16 ----
__device__ __forceinline__ uint4 dq_quad(const int wt[4], h2 ss) {
    uint32_t t0 = __builtin_amdgcn_perm((uint32_t)wt[1], (uint32_t)wt[0], 0x0C0C0400u);
    uint32_t t1 = __builtin_amdgcn_perm((uint32_t)wt[3], (uint32_t)wt[2], 0x04000C0Cu);
    uint32_t w4 = t0 | t1;
    const uint32_t T_LO = 0x56545000u; // codes 0..3 f16-hi of val*64
    const uint32_t T_HI = 0x5E5C5A58u; // codes 4..7
    uint32_t selL = w4 & 0x07070707u;
    uint32_t selH = (w4 >> 4) & 0x07070707u;
    uint32_t hiL = __builtin_amdgcn_perm(T_HI, T_LO, selL) | ((w4 & 0x08080808u) << 4);
    uint32_t hiH = __builtin_amdgcn_perm(T_HI, T_LO, selH) | (w4 & 0x80808080u);
    uint32_t p0 = __builtin_amdgcn_perm(hiH, hiL, 0x040C000Cu);
    uint32_t p1 = __builtin_amdgcn_perm(hiH, hiL, 0x050C010Cu);
    uint32_t p2 = __builtin_amdgcn_perm(hiH, hiL, 0x060C020Cu);
    uint32_t p3 = __builtin_amdgcn_perm(hiH, hiL, 0x070C030Cu);
    uint4 q;
    h2 r0 = *(h2*)&p0 * ss; __builtin_memcpy(&q.x, &r0, 4);
    h2 r1 = *(h2*)&p1 * ss; __builtin_memcpy(&q.y, &r1, 4);
    h2 r2 = *(h2*)&p2 * ss; __builtin_memcpy(&q.z, &r2, 4);
    h2 r3 = *(h2*)&p3 * ss; __builtin_memcpy(&q.w, &r3, 4);
    return q;
}

// ==================== prepass: x fp32 -> f16 once (removes per-block re-convert) ====
__global__ __launch_bounds__(256) void pack_x_kernel(const float* __restrict__ src,
                                                     ushort_t* __restrict__ dst) {
    const size_t total8 = (size_t)E_ * T_ * H_ / 8;
    const size_t stride = (size_t)gridDim.x * 256;
    for (size_t i = (size_t)blockIdx.x * 256 + threadIdx.x; i < total8; i += stride) {
        const float4 a = *(const float4*)(src + i * 8);
        const float4 b = *(const float4*)(src + i * 8 + 4);
        uint4 d;
        d.x = pk2h(a.x, a.y); d.y = pk2h(a.z, a.w);
        d.z = pk2h(b.x, b.y); d.w = pk2h(b.z, b.w);
        *(uint4*)(dst + i * 8) = d;
    }
}

// ==================== GEMM1: x @ dequant(Wgu) + silu, pipelined ====================
// Round-5 verified structure. XH=1: A comes pre-converted f16 (pure uint4 copy,
// -8 pk2h and -8 live VGPRs per thread). XH=0: original fp32 convert path.
template<int XH>
__global__ __launch_bounds__(512, 4) void gemm1_kernel(
    const float* __restrict__ x,
    const ushort_t* __restrict__ xh,
    const int* __restrict__ gup,
    const float* __restrict__ gus,
    const float* __restrict__ gscale_p,
    ushort_t* __restrict__ inter,
    int e0) {
    __shared__ __align__(16) ushort_t As[2][256 * 40];
    __shared__ __align__(16) ushort_t Bs[2][128 * 40];

    const int tid = threadIdx.x;
    const int lane = tid & 63, wv = tid >> 6;
    const int quad = lane >> 4, c16 = lane & 15;
    const int mw = wv >> 1, nw = wv & 1;
    const int zloc = blockIdx.z, e = e0 + zloc;
    const int mBase = blockIdx.y * 256, nTile = blockIdx.x;
    const float gsc = gscale_p[0];

    const int kq = (tid >> 4) & 3;
    const int bn = (tid & 15) | ((tid >> 6) << 4);
    const int colg = nTile * 64 + (bn & 63) + ((bn >> 6) << 12);
    const int* bptr = gup + (size_t)e * (H_ / 2) * N1_ + (size_t)(kq * 4) * N1_ + colg;
    const float* sptr = gus + (size_t)e * (H_ / 16) * N1_ + (size_t)(kq >> 1) * N1_ + colg;

    const int arow = tid >> 2, seg = tid & 3;
    const float* ap = x + (size_t)(e * T_ + mBase + arow) * H_ + seg * 8;
    const ushort_t* aph = xh + (size_t)(e * T_ + mBase + arow) * H_ + seg * 8;

    f32x4 accg[4][2], accu[4][2];
    const f32x4 z4 = {0.f, 0.f, 0.f, 0.f};
#pragma unroll
    for (int f = 0; f < 4; ++f)
#pragma unroll
        for (int b = 0; b < 2; ++b) { accg[f][b] = z4; accu[f][b] = z4; }

    float4 fa[4]; uint4 va[2]; int wt[4]; float sv;

#define G1_LOAD(t) do { \
    if constexpr (XH) { \
        va[0] = *(const uint4*)(aph + (size_t)(t) * 32); \
        va[1] = *(const uint4*)(aph + (size_t)128 * H_ + (size_t)(t) * 32); \
    } else { \
        fa[0] = *(const float4*)(ap + (size_t)(t) * 32); \
        fa[1] = *(const float4*)(ap + (size_t)(t) * 32 + 4); \
        fa[2] = *(const float4*)(ap + (size_t)128 * H_ + (size_t)(t) * 32); \
        fa[3] = *(const float4*)(ap + (size_t)128 * H_ + (size_t)(t) * 32 + 4); \
    } \
    const int* bp_ = bptr + (size_t)(t) * 16 * N1_; \
    wt[0] = bp_[0]; wt[1] = bp_[(size_t)N1_]; \
    wt[2] = bp_[2 * (size_t)N1_]; wt[3] = bp_[3 * (size_t)N1_]; \
    sv = sptr[(size_t)(t) * 2 * N1_] * gsc; \
} while (0)

#define G1_STAGE(L) do { \
    if constexpr (XH) { \
        *(uint4*)(&As[L][arow * 40 + seg * 8]) = va[0]; \
        *(uint4*)(&As[L][(arow + 128) * 40 + seg * 8]) = va[1]; \
    } else { \
        uint4 d0_, d1_; \
        d0_.x = pk2h(fa[0].x, fa[0].y); d0_.y = pk2h(fa[0].z, fa[0].w); \
        d0_.z = pk2h(fa[1].x, fa[1].y); d0_.w = pk2h(fa[1].z, fa[1].w); \
        d1_.x = pk2h(fa[2].x, fa[2].y); d1_.y = pk2h(fa[2].z, fa[2].w); \
        d1_.z = pk2h(fa[3].x, fa[3].y); d1_.w = pk2h(fa[3].z, fa[3].w); \
        *(uint4*)(&As[L][arow * 40 + seg * 8]) = d0_; \
        *(uint4*)(&As[L][(arow + 128) * 40 + seg * 8]) = d1_; \
    } \
    uint4 q_ = dq_quad(wt, mk_ss(sv)); \
    *(uint4*)(&Bs[L][bn * 40 + kq * 8]) = q_; \
} while (0)

#define G1_CONSUME(L) do { \
    f16x8 bg0 = *(const f16x8*)(&Bs[L][(nw * 32 + c16) * 40 + quad * 8]); \
    f16x8 bg1 = *(const f16x8*)(&Bs[L][(nw * 32 + 16 + c16) * 40 + quad * 8]); \
    f16x8 bu0 = *(const f16x8*)(&Bs[L][(64 + nw * 32 + c16) * 40 + quad * 8]); \
    f16x8 bu1 = *(const f16x8*)(&Bs[L][(64 + nw * 32 + 16 + c16) * 40 + quad * 8]); \
    _Pragma("unroll") \
    for (int f = 0; f < 4; ++f) { \
        f16x8 af = *(const f16x8*)(&As[L][(mw * 64 + f * 16 + c16) * 40 + quad * 8]); \
        accg[f][0] = __builtin_amdgcn_mfma_f32_16x16x32_f16(af, bg0, accg[f][0], 0, 0, 0); \
        accg[f][1] = __builtin_amdgcn_mfma_f32_16x16x32_f16(af, bg1, accg[f][1], 0, 0, 0); \
        accu[f][0] = __builtin_amdgcn_mfma_f32_16x16x32_f16(af, bu0, accu[f][0], 0, 0, 0); \
        accu[f][1] = __builtin_amdgcn_mfma_f32_16x16x32_f16(af, bu1, accu[f][1], 0, 0, 0); \
    } \
} while (0)

    // ---- prologue: tile 0 ---- (verified round-5 schedule: 1-deep prefetch)
    G1_LOAD(0);
    G1_STAGE(0);
    __syncthreads();

    for (int kt = 0; kt < H_ / 32 - 1; ++kt) {
        const int cur = kt & 1, nxt = cur ^ 1;
        G1_LOAD(kt + 1);
        G1_CONSUME(cur);
        G1_STAGE(nxt);
        __syncthreads();
    }
    G1_CONSUME((H_ / 32 - 1) & 1);
#undef G1_LOAD
#undef G1_STAGE
#undef G1_CONSUME

    // epilogue: inter = up * silu(gate), stored as f16
    ushort_t* ip = inter + (size_t)zloc * T_ * I_;
#pragma unroll
    for (int f = 0; f < 4; ++f)
#pragma unroll
        for (int b = 0; b < 2; ++b)
#pragma unroll
            for (int r = 0; r < 4; ++r) {
                int row = mBase + mw * 64 + f * 16 + quad * 4 + r;
                int col = nTile * 64 + nw * 32 + b * 16 + c16;
                float g = accg[f][b][r];
                float u = accu[f][b][r];
                float v = u * g / (1.f + __expf(-g));
                half_t hv = (half_t)v;
                ushort_t hu;
                __builtin_memcpy(&hu, &hv, 2);
                ip[(size_t)row * I_ + col] = hu;
            }
}

// ==================== GEMM2: inter(f16) @ dequant(Wd) -> fp32 ====================
// (verified round-5 kernel, unchanged)
__global__ __launch_bounds__(512, 4) void gemm2_kernel(
    const ushort_t* __restrict__ inter,
    const int* __restrict__ dp,
    const float* __restrict__ dsc,
    const float* __restrict__ gscale_p,
    float* __restrict__ out,
    int e0) {
    __shared__ __align__(16) ushort_t As[2][256 * 40];
    __shared__ __align__(16) ushort_t Bs[2][128 * 40];

    const int tid = threadIdx.x;
    const int lane = tid & 63, wv = tid >> 6;
    const int quad = lane >> 4, c16 = lane & 15;
    const int mw = wv >> 1, nw = wv & 1;
    const int zloc = blockIdx.z, e = e0 + zloc;
    const int mBase = blockIdx.y * 256, nBase = blockIdx.x * 128;
    const float gsc = gscale_p[0];

    const int kq = (tid >> 4) & 3;
    const int bn = (tid & 15) | ((tid >> 6) << 4);
    const int col = nBase + bn;
    const int* bptr = dp + (size_t)e * (I_ / 2) * H_ + (size_t)(kq * 4) * H_ + col;
    const float* sptr = dsc + (size_t)e * (I_ / 16) * H_ + (size_t)(kq >> 1) * H_ + col;

    const int arow = tid >> 2, seg = tid & 3;
    const ushort_t* ap = inter + (size_t)(zloc * T_ + mBase + arow) * I_ + seg * 8;

    f32x4 acc[4][4];
    const f32x4 z4 = {0.f, 0.f, 0.f, 0.f};
#pragma unroll
    for (int f = 0; f < 4; ++f)
#pragma unroll
        for (int b = 0; b < 4; ++b) acc[f][b] = z4;

    uint4 va[2]; int wt[4]; float sv;
    // ---- prologue: tile 0 ----
#pragma unroll
    for (int p = 0; p < 2; ++p) va[p] = *(const uint4*)(ap + (size_t)(p * 128) * I_);
#pragma unroll
    for (int i = 0; i < 4; ++i) wt[i] = bptr[(size_t)i * H_];
    sv = sptr[0] * gsc;
    {
#pragma unroll
        for (int p = 0; p < 2; ++p)
            *(uint4*)(&As[0][(arow + p * 128) * 40 + seg * 8]) = va[p];
        uint4 q = dq_quad(wt, mk_ss(sv));
        *(uint4*)(&Bs[0][bn * 40 + kq * 8]) = q;
    }
    __syncthreads();

    for (int kt = 0; kt < I_ / 32 - 1; ++kt) {
        const int cur = kt & 1, nxt = cur ^ 1;
        // ---- prefetch tile kt+1 ----
#pragma unroll
        for (int p = 0; p < 2; ++p)
            va[p] = *(const uint4*)(ap + (size_t)(p * 128) * I_ + (kt + 1) * 32);
        const int* bp = bptr + (size_t)(kt + 1) * 16 * H_;
#pragma unroll
        for (int i = 0; i < 4; ++i) wt[i] = bp[(size_t)i * H_];
        sv = sptr[(size_t)(kt + 1) * 2 * H_] * gsc;

        // ---- consume current ----
        f16x8 bfr[4];
#pragma unroll
        for (int b = 0; b < 4; ++b)
            bfr[b] = *(const f16x8*)(&Bs[cur][(nw * 64 + b * 16 + c16) * 40 + quad * 8]);
#pragma unroll
        for (int f = 0; f < 4; ++f) {
            f16x8 af = *(const f16x8*)(&As[cur][(mw * 64 + f * 16 + c16) * 40 + quad * 8]);
#pragma unroll
            for (int b = 0; b < 4; ++b)
                acc[f][b] = __builtin_amdgcn_mfma_f32_16x16x32_f16(af, bfr[b], acc[f][b], 0, 0, 0);
        }

        // ---- stage next ----
#pragma unroll
        for (int p = 0; p < 2; ++p)
            *(uint4*)(&As[nxt][(arow + p * 128) * 40 + seg * 8]) = va[p];
        uint4 q = dq_quad(wt, mk_ss(sv));
        *(uint4*)(&Bs[nxt][bn * 40 + kq * 8]) = q;
        __syncthreads();
    }

    // ---- last tile ----
    {
        const int cur = (I_ / 32 - 1) & 1;
        f16x8 bfr[4];
#pragma unroll
        for (int b = 0; b < 4; ++b)
            bfr[b] = *(const f16x8*)(&Bs[cur][(nw * 64 + b * 16 + c16) * 40 + quad * 8]);
#pragma unroll
        for (int f = 0; f < 4; ++f) {
            f16x8 af = *(const f16x8*)(&As[cur][(mw * 64 + f * 16 + c16) * 40 + quad * 8]);
#pragma unroll
            for (int b = 0; b < 4; ++b)
                acc[f][b] = __builtin_amdgcn_mfma_f32_16x16x32_f16(af, bfr[b], acc[f][b], 0, 0, 0);
        }
    }

#pragma unroll
    for (int f = 0; f < 4; ++f)
#pragma unroll
        for (int b = 0; b < 4; ++b)
#pragma unroll
            for (int r = 0; r < 4; ++r) {
                int row = mBase + mw * 64 + f * 16 + quad * 4 + r;
                int c = nBase + nw * 64 + b * 16 + c16;
                out[(size_t)(e * T_ + row) * H_ + c] = acc[f][b][r];
            }
}

extern "C" void kernel_launch(void* const* d_in, const int* in_sizes, int n_in,
                              void* d_out, int out_size, void* d_ws, size_t ws_size,
                              hipStream_t stream) {
    const float* x = (const float*)d_in[0];
    const int* gup = (const int*)d_in[1];
    const float* gus = (const float*)d_in[2];
    const float* gug = (const float*)d_in[3];
    const int* dp = (const int*)d_in[4];
    const float* dsc = (const float*)d_in[5];
    const float* dg = (const float*)d_in[6];
    float* out = (float*)d_out;
    uint8_t* wsb = (uint8_t*)d_ws;
    ushort_t* inter = (ushort_t*)wsb;

    const size_t per_e = (size_t)T_ * I_ * 2;             // 8.39 MB
    const size_t xh_b = (size_t)E_ * T_ * H_ * 2;         // 32 MB

    // xh lives at the top of ws; use it if enough room remains for C>=2 batching.
    int use_xh = 0; size_t avail = ws_size;
    if (ws_size >= xh_b + 2 * per_e) { use_xh = 1; avail = ws_size - xh_b; }
    int C = avail >= 8 * per_e ? 8 : avail >= 4 * per_e ? 4 : avail >= 2 * per_e ? 2 : 1;

    ushort_t* xhp = (ushort_t*)(wsb + ((ws_size - (use_xh ? xh_b : 0)) & ~(size_t)15));
    const ushort_t* xh_arg = use_xh ? (const ushort_t*)xhp : (const ushort_t*)wsb;

    if (use_xh) pack_x_kernel<<<2048, 256, 0, stream>>>(x, xhp);

    for (int e0 = 0; e0 < E_; e0 += C) {
        dim3 g1(I_ / 64, T_ / 256, C), g2(H_ / 128, T_ / 256, C);
        if (use_xh)
            gemm1_kernel<1><<<g1, 512, 0, stream>>>(x, xh_arg, gup, gus, gug, inter, e0);
        else
            gemm1_kernel<0><<<g1, 512, 0, stream>>>(x, xh_arg, gup, gus, gug, inter, e0);
        gemm2_kernel<<<g2, 512, 0, stream>>>(inter, dp, dsc, dg, out, e0);
    }
}